// Round 9
// baseline (430.826 us; speedup 1.0000x reference)
//
#include <hip/hip_runtime.h>
#include <hip/hip_fp16.h>

#define HID 128     // both IN_DIM and hidden dim are 128
#define NN 50000    // node count (fixed by the problem)
#define NW4 (NN / 4)  // u8-packed histogram words per row = 12500
#define NB 256      // edge-chunk blocks: chunk = 3125 -> per-(block,node) count << 256
#define CST 64      // padded CSR row stride (max in-degree ~45 for Poisson(16))

typedef _Float16 f16;
typedef f16 f16x8 __attribute__((ext_vector_type(8)));
typedef float f32x4 __attribute__((ext_vector_type(4)));

// ---- e5m2 fp8 via bit-slicing of fp16 (no header/builtin dependence) ------
__device__ __forceinline__ unsigned char enc8(float v) {
  __half h = __float2half(v);
  unsigned short b;
  __builtin_memcpy(&b, &h, 2);
  return (unsigned char)((b + 0x80u) >> 8);   // round-half-up into e5m2
}
__device__ __forceinline__ float2 dec8x2(unsigned short v) {  // 2 packed e5m2
  unsigned packed = ((unsigned)(v << 8) & 0xff00u) | (((unsigned)v & 0xff00u) << 16);
  __half2 h2;
  __builtin_memcpy(&h2, &packed, 4);
  return __half22float2(h2);
}
__device__ __forceinline__ f16x8 dec8x8(const unsigned char* p) {  // 8 packed e5m2
  uint2 u = *(const uint2*)p;
  unsigned short s[8];
  s[0] = (u.x << 8) & 0xff00u;  s[1] = u.x & 0xff00u;
  s[2] = (u.x >> 8) & 0xff00u;  s[3] = (u.x >> 16) & 0xff00u;
  s[4] = (u.y << 8) & 0xff00u;  s[5] = u.y & 0xff00u;
  s[6] = (u.y >> 8) & 0xff00u;  s[7] = (u.y >> 16) & 0xff00u;
  f16x8 r;
  __builtin_memcpy(&r, s, 16);
  return r;
}

// ---------------------------------------------------------------------------
// CSR build phase 1: per-block PRIVATE LDS histograms, u8 x4 packed.
// (R3: global atomics write through to HBM at 32B/op regardless of scope;
// LDS atomics don't. ds_add_rtn byte = edge rank.) Also zeroes d_out
// (read only by the final loss kernel -- saves the memset dispatch).
// ---------------------------------------------------------------------------
__global__ __launch_bounds__(256) void hist_kernel(
    const int* __restrict__ src, const int* __restrict__ dst,
    unsigned* __restrict__ pin, unsigned* __restrict__ pout,
    unsigned char* __restrict__ rank, float* __restrict__ d_out_f,
    int E, int chunk) {
  __shared__ unsigned hist[NW4];    // 50 KB -> 3 blocks/CU
  const int b = blockIdx.x;
  const int e0 = b * chunk, e1 = min(E, e0 + chunk);
  if (b == 0 && threadIdx.x == 0) *d_out_f = 0.f;

  for (int i = threadIdx.x; i < NW4; i += 256) hist[i] = 0;
  __syncthreads();
  for (int e = e0 + threadIdx.x; e < e1; e += 256) {
    int d = dst[e];
    unsigned sh = 8u * (d & 3);
    unsigned old = atomicAdd(&hist[d >> 2], 1u << sh);   // LDS atomic
    rank[e] = (unsigned char)((old >> sh) & 0xffu);
  }
  __syncthreads();
  unsigned* rowI = pin + (size_t)b * NW4;
  for (int i = threadIdx.x; i < NW4; i += 256) rowI[i] = hist[i];
  __syncthreads();                  // row dump done before re-zero
  for (int i = threadIdx.x; i < NW4; i += 256) hist[i] = 0;
  __syncthreads();
  for (int e = e0 + threadIdx.x; e < e1; e += 256) {
    int s = src[e];
    atomicAdd(&hist[s >> 2], 1u << (8u * (s & 3)));
  }
  __syncthreads();
  unsigned* rowO = pout + (size_t)b * NW4;
  for (int i = threadIdx.x; i < NW4; i += 256) rowO[i] = hist[i];
}

// ---------------------------------------------------------------------------
// CSR build phase 2: scan over the 256 hist blocks, parallel in both axes
// (R4: serial-b version was latency-starved at 1.9% occupancy). Block =
// 32 words x 8 tiles; per-thread 32 b's in registers, in-register exclusive
// prefix, 8-tile LDS scan. u8x4-packed arithmetic (degrees << 256: no carry).
// ---------------------------------------------------------------------------
__global__ __launch_bounds__(256) void merge_kernel(
    unsigned* __restrict__ pin, const unsigned* __restrict__ pout,
    int* __restrict__ in_cnt, float* __restrict__ ns, float* __restrict__ nd) {
  __shared__ unsigned tsum[8][32];
  __shared__ unsigned osum[8][32];
  const int wl = threadIdx.x & 31;   // word slot within block
  const int tile = threadIdx.x >> 5; // 0..7 -> b's [tile*32, tile*32+32)
  const int w = blockIdx.x * 32 + wl;
  const bool ok = w < NW4;

  unsigned v[32];
  unsigned s = 0, so = 0;
  if (ok) {
#pragma unroll
    for (int j = 0; j < 32; ++j)
      v[j] = pin[(size_t)(tile * 32 + j) * NW4 + w];
#pragma unroll
    for (int j = 0; j < 32; ++j) {  // in-register exclusive prefix (packed)
      unsigned x = v[j];
      v[j] = s;
      s += x;
    }
#pragma unroll
    for (int j = 0; j < 32; ++j)
      so += pout[(size_t)(tile * 32 + j) * NW4 + w];
  }
  tsum[tile][wl] = s;
  osum[tile][wl] = so;
  __syncthreads();
  unsigned toff = 0;
  for (int k = 0; k < tile; ++k) toff += tsum[k][wl];
  if (ok) {
#pragma unroll
    for (int j = 0; j < 32; ++j)
      pin[(size_t)(tile * 32 + j) * NW4 + w] = v[j] + toff;
    if (tile == 7) {
      unsigned tin = toff + s;      // packed in-degrees of the 4 nodes
      unsigned tout = 0;
#pragma unroll
      for (int k = 0; k < 8; ++k) tout += osum[k][wl];
      int i0 = tin & 0xffu, i1 = (tin >> 8) & 0xffu,
          i2 = (tin >> 16) & 0xffu, i3 = (tin >> 24) & 0xffu;
      int o0 = tout & 0xffu, o1 = (tout >> 8) & 0xffu,
          o2 = (tout >> 16) & 0xffu, o3 = (tout >> 24) & 0xffu;
      ((int4*)in_cnt)[w] = make_int4(i0, i1, i2, i3);
      ((float4*)nd)[w] = make_float4(rsqrtf((float)max(i0, 1)),
                                     rsqrtf((float)max(i1, 1)),
                                     rsqrtf((float)max(i2, 1)),
                                     rsqrtf((float)max(i3, 1)));
      ((float4*)ns)[w] = make_float4(rsqrtf((float)max(o0, 1)),
                                     rsqrtf((float)max(o1, 1)),
                                     rsqrtf((float)max(o2, 1)),
                                     rsqrtf((float)max(o3, 1)));
    }
  }
}

// ---------------------------------------------------------------------------
// Fused phase 3 (everything that depends only on merge, disjoint outputs):
//   blocks [0,256):    atomic-free CSR fill (padded, stride 64/node)
//   blocks [256,512):  weight transpose -> fp16 Wt[m][n][k]
//   blocks [512,...):  X0 = enc8(ns[row] * attr[row])  (ns prescaled)
// ---------------------------------------------------------------------------
__global__ __launch_bounds__(256) void fillprep_kernel(
    const int* __restrict__ src, const int* __restrict__ dst,
    const unsigned char* __restrict__ rank, const unsigned* __restrict__ pin,
    int* __restrict__ csr,
    const float* __restrict__ attr, const float* __restrict__ Ws,
    const float* __restrict__ decW, const float* __restrict__ ns,
    unsigned char* __restrict__ X, f16* __restrict__ Wt,
    int E, int chunk, int n4) {
  const int b = blockIdx.x;
  if (b < 256) {
    const int e0 = b * chunk, e1 = min(E, e0 + chunk);
    const unsigned* __restrict__ row = pin + (size_t)b * NW4;
    for (int e = e0 + threadIdx.x; e < e1; e += 256) {
      int s = src[e], d = dst[e];
      unsigned base = (row[d >> 2] >> (8u * (d & 3))) & 0xffu;
      csr[d * CST + (int)base + (int)rank[e]] = s;
    }
  } else if (b < 512) {
    int i = (b - 256) * 256 + threadIdx.x;    // exactly 4*128*128
    int m = i >> 14, rem = i & 16383, n = rem >> 7, k = rem & 127;
    const float* Wsrc = (m < 3) ? (Ws + (size_t)m * 16384) : decW;
    Wt[i] = (f16)Wsrc[k * 128 + n];
  } else {
    int i = (b - 512) * 256 + threadIdx.x;
    if (i < n4) {
      int r = i >> 5;
      float s = ns[r];
      float4 v = ((const float4*)attr)[i];
      ((uchar4*)X)[i] = make_uchar4(enc8(s * v.x), enc8(s * v.y),
                                    enc8(s * v.z), enc8(s * v.w));
    }
  }
}

__global__ void mask_h_kernel(unsigned char* __restrict__ h,
                              const int* __restrict__ mask,
                              const float* __restrict__ token,
                              const float* __restrict__ ns, int n4) {
  int i = blockIdx.x * blockDim.x + threadIdx.x;
  if (i < n4) {
    int r = i >> 5, c4 = i & 31;       // 32 uchar4 per 128-wide row
    int row = mask[r];
    float s = ns[row];
    float4 v = ((const float4*)token)[c4];
    *(uchar4*)(h + (size_t)row * HID + c4 * 4) =
        make_uchar4(enc8(s * v.x), enc8(s * v.y), enc8(s * v.z), enc8(s * v.w));
  }
}

// ---------------------------------------------------------------------------
// FUSED layer kernel (R8): aggregation + MFMA GEMM in one dispatch; the
// aggregated tile never leaves the CU (f16 in LDS -- kills the Y global
// round-trip and the producer->consumer device drain per layer).
//   Phase A: wave w aggregates nodes [mBase+w*16, +16): csr row in ONE
//     coalesced 64-lane load, __shfl feeds each edge's index; X rows are
//     fp8-e5m2 and ns-prescaled, fp32 accumulate, * nd -> f16 -> LDS tile
//     Yt (stride 136 halves: every access phase <=2-way = free).
//   Phase B: the SAME wave reads its own 16 rows back as A-fragments
//     (no cross-wave dep; the one __syncthreads covers Bs staging) and
//     runs 8 n-tiles x 4 k-iters of mfma_f32_16x16x32_f16.
//   Epilogue: relu(acc+bias)[*ns] -> fp8 Xout. Xin/Xout MUST ping-pong
//   (other blocks' agg still reads Xin).
// LDS 52.2 KB -> 3 blocks/CU. Layouts (HW-verified): A[m=lane&15]
// [k=(lane>>4)*8+j]; C/D col=lane&15, row=(lane>>4)*4+reg.
// ---------------------------------------------------------------------------
__global__ __launch_bounds__(256) void layer_kernel(
    const unsigned short* __restrict__ Xin, const int* __restrict__ csr,
    const int* __restrict__ in_cnt, const float* __restrict__ nd,
    const f16* __restrict__ Wt, const float* __restrict__ col_bias,
    const float* __restrict__ row_scale, unsigned char* __restrict__ Xout,
    int N) {
  __shared__ f16 Bs[128 * 136];     // 34.8 KB
  __shared__ f16 Yt[64 * 136];      // 17.4 KB agg tile
  const int t = threadIdx.x;
  for (int i = t; i < 2048; i += 256) {
    int n = i >> 4, c = i & 15;
    *(f16x8*)&Bs[n * 136 + c * 8] = *(const f16x8*)&Wt[n * 128 + c * 8];
  }
  const int wave = t >> 6, lane = t & 63;
  const int mBase = blockIdx.x * 64;

  // ---- Phase A: aggregate 16 nodes per wave ----
  for (int i = 0; i < 16; ++i) {
    int nl = wave * 16 + i;
    int node = mBase + nl;
    int safe = (node < N) ? node : 0;
    int cnt = (node < N) ? in_cnt[safe] : 0;
    int idx = csr[safe * CST + lane];   // whole padded row, one load
    float2 acc = make_float2(0.f, 0.f);
    int j = 0;
    for (; j + 4 <= cnt; j += 4) {
      int s0 = __shfl(idx, j + 0);
      int s1 = __shfl(idx, j + 1);
      int s2 = __shfl(idx, j + 2);
      int s3 = __shfl(idx, j + 3);
      float2 v0 = dec8x2(Xin[(size_t)s0 * 64 + lane]);
      float2 v1 = dec8x2(Xin[(size_t)s1 * 64 + lane]);
      float2 v2 = dec8x2(Xin[(size_t)s2 * 64 + lane]);
      float2 v3 = dec8x2(Xin[(size_t)s3 * 64 + lane]);
      acc.x += (v0.x + v1.x) + (v2.x + v3.x);
      acc.y += (v0.y + v1.y) + (v2.y + v3.y);
    }
    for (; j < cnt; ++j) {
      int s = __shfl(idx, j);
      float2 v = dec8x2(Xin[(size_t)s * 64 + lane]);
      acc.x += v.x;
      acc.y += v.y;
    }
    float ndv = nd[safe];
    __half2 hv = __floats2half2_rn(acc.x * ndv, acc.y * ndv);
    *(__half2*)&Yt[nl * 136 + lane * 2] = hv;
  }
  __syncthreads();                    // Bs staged + (wave-local) Yt written

  // ---- Phase B: GEMM on the tile ----
  const int ln = lane & 15, kq = lane >> 4;
  const int arow = wave * 16 + ln;
  f16x8 af[4];
#pragma unroll
  for (int ki = 0; ki < 4; ++ki)
    af[ki] = *(const f16x8*)&Yt[arow * 136 + ki * 32 + kq * 8];

  f32x4 acc[8];
#pragma unroll
  for (int nt = 0; nt < 8; ++nt) acc[nt] = (f32x4){0.f, 0.f, 0.f, 0.f};
#pragma unroll
  for (int ki = 0; ki < 4; ++ki) {
#pragma unroll
    for (int nt = 0; nt < 8; ++nt) {
      f16x8 bf = *(const f16x8*)&Bs[(nt * 16 + ln) * 136 + ki * 32 + kq * 8];
      acc[nt] = __builtin_amdgcn_mfma_f32_16x16x32_f16(af[ki], bf, acc[nt], 0, 0, 0);
    }
  }
  const int orow = mBase + wave * 16 + kq * 4;
  float rs[4];
#pragma unroll
  for (int r = 0; r < 4; ++r)
    rs[r] = (row_scale && orow + r < N) ? row_scale[orow + r] : 1.f;
#pragma unroll
  for (int nt = 0; nt < 8; ++nt) {
    int col = nt * 16 + ln;
    float bb = col_bias[col];
#pragma unroll
    for (int r = 0; r < 4; ++r) {
      int gr = orow + r;
      if (gr < N) {
        float v = fmaxf(acc[nt][r] + bb, 0.f) * rs[r];
        Xout[(size_t)gr * HID + col] = enc8(v);
      }
    }
  }
}

// ---------------------------------------------------------------------------
// Decoder GEMM with FUSED loss: recon rows never hit memory. Per block:
// acc -> (recon - attr[mask[row]])^2 -> wave reduce -> one atomic.
// ---------------------------------------------------------------------------
__global__ __launch_bounds__(256) void gemm_loss_kernel(
    const unsigned char* __restrict__ A8, const f16* __restrict__ Wt,
    const float* __restrict__ col_bias, const int* __restrict__ gather,
    const float* __restrict__ attr, float* __restrict__ out, int M, float scale) {
  __shared__ f16 Bs[128 * 136];
  const int t = threadIdx.x;
  for (int i = t; i < 2048; i += 256) {
    int n = i >> 4, c = i & 15;
    *(f16x8*)&Bs[n * 136 + c * 8] = *(const f16x8*)&Wt[n * 128 + c * 8];
  }
  const int wave = t >> 6, lane = t & 63;
  const int ln = lane & 15, kq = lane >> 4;
  const int mBase = blockIdx.x * 64 + wave * 16;

  const int am = mBase + ln;
  const int rowA = (am < M) ? gather[am] : 0;
  const unsigned char* Ap = A8 + (size_t)rowA * HID + kq * 8;
  f16x8 af[4];
#pragma unroll
  for (int ki = 0; ki < 4; ++ki) af[ki] = dec8x8(Ap + ki * 32);

  f32x4 acc[8];
#pragma unroll
  for (int nt = 0; nt < 8; ++nt) acc[nt] = (f32x4){0.f, 0.f, 0.f, 0.f};
  __syncthreads();
#pragma unroll
  for (int ki = 0; ki < 4; ++ki) {
#pragma unroll
    for (int nt = 0; nt < 8; ++nt) {
      f16x8 bf = *(const f16x8*)&Bs[(nt * 16 + ln) * 136 + ki * 32 + kq * 8];
      acc[nt] = __builtin_amdgcn_mfma_f32_16x16x32_f16(af[ki], bf, acc[nt], 0, 0, 0);
    }
  }
  const int orow = mBase + kq * 4;
  int mrow[4];
#pragma unroll
  for (int r = 0; r < 4; ++r) mrow[r] = (orow + r < M) ? gather[orow + r] : -1;
  float part = 0.f;
#pragma unroll
  for (int nt = 0; nt < 8; ++nt) {
    int col = nt * 16 + ln;
    float bb = col_bias[col];
#pragma unroll
    for (int r = 0; r < 4; ++r) {
      if (mrow[r] >= 0) {
        float d = acc[nt][r] + bb - attr[(size_t)mrow[r] * HID + col];
        part += d * d;
      }
    }
  }
#pragma unroll
  for (int off = 32; off > 0; off >>= 1) part += __shfl_down(part, off);
  __shared__ float wsum[4];
  if (lane == 0) wsum[wave] = part;
  __syncthreads();
  if (t == 0)
    atomicAdd(out, (wsum[0] + wsum[1] + wsum[2] + wsum[3]) * scale);
}

// ---------------------------------------------------------------------------
extern "C" void kernel_launch(void* const* d_in, const int* in_sizes, int n_in,
                              void* d_out, int out_size, void* d_ws, size_t ws_size,
                              hipStream_t stream) {
  const float* attr  = (const float*)d_in[0];
  const int*   src   = (const int*)d_in[1];
  const int*   dst   = (const int*)d_in[2];
  const float* Ws    = (const float*)d_in[3];
  const float* bs    = (const float*)d_in[4];
  const float* decW  = (const float*)d_in[5];
  const float* decb  = (const float*)d_in[6];
  const float* token = (const float*)d_in[7];
  const int*   mask  = (const int*)d_in[8];

  const int N  = in_sizes[0] / HID;   // 50000
  const int E  = in_sizes[1];         // 800000
  const int NM = in_sizes[8];         // 15000
  const int chunk = (E + NB - 1) / NB;  // 3125

  // Workspace layout (16B-aligned pieces; total ~53 MB)
  char* w = (char*)d_ws;
  unsigned char* X0 = (unsigned char*)w;  w += (size_t)N * HID;  // fp8 ping
  unsigned char* X1 = (unsigned char*)w;  w += (size_t)N * HID;  // fp8 pong
  f16* Wt = (f16*)w;           w += (size_t)4 * HID * HID * 2;
  int* csr = (int*)w;          w += (size_t)NN * CST * 4;        // padded CSR
  unsigned char* rank = (unsigned char*)w;  w += (size_t)E;
  unsigned* pin = (unsigned*)w;  w += (size_t)NB * NW4 * 4;
  unsigned* pout = (unsigned*)w; w += (size_t)NB * NW4 * 4;
  int* in_cnt = (int*)w;       w += (size_t)N * 4;
  float* ns = (float*)w;       w += (size_t)N * 4;
  float* nd = (float*)w;       w += (size_t)N * 4;

  hist_kernel<<<NB, 256, 0, stream>>>(src, dst, pin, pout, rank,
                                      (float*)d_out, E, chunk);
  merge_kernel<<<(NW4 + 31) / 32, 256, 0, stream>>>(pin, pout, in_cnt, ns, nd);

  int prep_blocks = 512 + (N * 32 + 255) / 256;
  fillprep_kernel<<<prep_blocks, 256, 0, stream>>>(
      src, dst, rank, pin, csr, attr, Ws, decW, ns, X0, Wt, E, chunk, N * 32);
  mask_h_kernel<<<(NM * 32 + 255) / 256, 256, 0, stream>>>(X0, mask, token, ns, NM * 32);

  // layer l: Xout = relu((nd*Agg(Xin)) @ W_l + b_l) [* ns for l<2], ping-pong
  unsigned char* Xi = X0;
  unsigned char* Xo = X1;
  for (int l = 0; l < 3; ++l) {
    layer_kernel<<<(N + 63) / 64, 256, 0, stream>>>(
        (const unsigned short*)Xi, csr, in_cnt, nd,
        Wt + (size_t)l * HID * HID, bs + (size_t)l * HID,
        (l < 2) ? ns : nullptr, Xo, N);
    unsigned char* tmp = Xi; Xi = Xo; Xo = tmp;
  }

  // loss = mean((Xi[mask] @ decW + decb - attr[mask])^2), recon never stored
  gemm_loss_kernel<<<(NM + 63) / 64, 256, 0, stream>>>(
      Xi, Wt + (size_t)3 * HID * HID, decb, mask, attr, (float*)d_out,
      NM, 1.f / ((float)NM * HID));
}

// Round 10
// 267.254 us; speedup vs baseline: 1.6120x; 1.6120x over previous
//
#include <hip/hip_runtime.h>
#include <hip/hip_fp16.h>

#define HID 128     // both IN_DIM and hidden dim are 128
#define NN 50000    // node count (fixed by the problem)
#define NW4 (NN / 4)  // u8-packed histogram words per row = 12500
#define NB 256      // edge-chunk blocks: chunk = 3125 -> per-(block,node) count << 256
#define CST 64      // padded CSR row stride (max in-degree ~45 for Poisson(16))

typedef _Float16 f16;
typedef f16 f16x8 __attribute__((ext_vector_type(8)));
typedef float f32x4 __attribute__((ext_vector_type(4)));

// ---- e5m2 fp8 via bit-slicing of fp16 (no header/builtin dependence) ------
__device__ __forceinline__ unsigned char enc8(float v) {
  __half h = __float2half(v);
  unsigned short b;
  __builtin_memcpy(&b, &h, 2);
  return (unsigned char)((b + 0x80u) >> 8);   // round-half-up into e5m2
}
__device__ __forceinline__ float2 dec8x2(unsigned short v) {  // 2 packed e5m2
  unsigned packed = ((unsigned)(v << 8) & 0xff00u) | (((unsigned)v & 0xff00u) << 16);
  __half2 h2;
  __builtin_memcpy(&h2, &packed, 4);
  return __half22float2(h2);
}
__device__ __forceinline__ f16x8 dec8x8(const unsigned char* p) {  // 8 packed e5m2
  uint2 u = *(const uint2*)p;
  unsigned short s[8];
  s[0] = (u.x << 8) & 0xff00u;  s[1] = u.x & 0xff00u;
  s[2] = (u.x >> 8) & 0xff00u;  s[3] = (u.x >> 16) & 0xff00u;
  s[4] = (u.y << 8) & 0xff00u;  s[5] = u.y & 0xff00u;
  s[6] = (u.y >> 8) & 0xff00u;  s[7] = (u.y >> 16) & 0xff00u;
  f16x8 r;
  __builtin_memcpy(&r, s, 16);
  return r;
}

// ---------------------------------------------------------------------------
// CSR build phase 1: per-block PRIVATE LDS histograms, u8 x4 packed.
// (R3: global atomics write through to HBM at 32B/op regardless of scope;
// LDS atomics don't. ds_add_rtn byte = edge rank.) Also zeroes d_out.
// ---------------------------------------------------------------------------
__global__ __launch_bounds__(256) void hist_kernel(
    const int* __restrict__ src, const int* __restrict__ dst,
    unsigned* __restrict__ pin, unsigned* __restrict__ pout,
    unsigned char* __restrict__ rank, float* __restrict__ d_out_f,
    int E, int chunk) {
  __shared__ unsigned hist[NW4];    // 50 KB -> 3 blocks/CU
  const int b = blockIdx.x;
  const int e0 = b * chunk, e1 = min(E, e0 + chunk);
  if (b == 0 && threadIdx.x == 0) *d_out_f = 0.f;

  for (int i = threadIdx.x; i < NW4; i += 256) hist[i] = 0;
  __syncthreads();
  for (int e = e0 + threadIdx.x; e < e1; e += 256) {
    int d = dst[e];
    unsigned sh = 8u * (d & 3);
    unsigned old = atomicAdd(&hist[d >> 2], 1u << sh);   // LDS atomic
    rank[e] = (unsigned char)((old >> sh) & 0xffu);
  }
  __syncthreads();
  unsigned* rowI = pin + (size_t)b * NW4;
  for (int i = threadIdx.x; i < NW4; i += 256) rowI[i] = hist[i];
  __syncthreads();                  // row dump done before re-zero
  for (int i = threadIdx.x; i < NW4; i += 256) hist[i] = 0;
  __syncthreads();
  for (int e = e0 + threadIdx.x; e < e1; e += 256) {
    int s = src[e];
    atomicAdd(&hist[s >> 2], 1u << (8u * (s & 3)));
  }
  __syncthreads();
  unsigned* rowO = pout + (size_t)b * NW4;
  for (int i = threadIdx.x; i < NW4; i += 256) rowO[i] = hist[i];
}

// ---------------------------------------------------------------------------
// CSR build phase 2: scan over the 256 hist blocks, parallel in both axes
// (R4: serial-b version was latency-starved at 1.9% occupancy). Block =
// 32 words x 8 tiles; per-thread 32 b's in registers, in-register exclusive
// prefix, 8-tile LDS scan. u8x4-packed arithmetic (degrees << 256: no carry).
// ---------------------------------------------------------------------------
__global__ __launch_bounds__(256) void merge_kernel(
    unsigned* __restrict__ pin, const unsigned* __restrict__ pout,
    int* __restrict__ in_cnt, float* __restrict__ ns, float* __restrict__ nd) {
  __shared__ unsigned tsum[8][32];
  __shared__ unsigned osum[8][32];
  const int wl = threadIdx.x & 31;   // word slot within block
  const int tile = threadIdx.x >> 5; // 0..7 -> b's [tile*32, tile*32+32)
  const int w = blockIdx.x * 32 + wl;
  const bool ok = w < NW4;

  unsigned v[32];
  unsigned s = 0, so = 0;
  if (ok) {
#pragma unroll
    for (int j = 0; j < 32; ++j)
      v[j] = pin[(size_t)(tile * 32 + j) * NW4 + w];
#pragma unroll
    for (int j = 0; j < 32; ++j) {  // in-register exclusive prefix (packed)
      unsigned x = v[j];
      v[j] = s;
      s += x;
    }
#pragma unroll
    for (int j = 0; j < 32; ++j)
      so += pout[(size_t)(tile * 32 + j) * NW4 + w];
  }
  tsum[tile][wl] = s;
  osum[tile][wl] = so;
  __syncthreads();
  unsigned toff = 0;
  for (int k = 0; k < tile; ++k) toff += tsum[k][wl];
  if (ok) {
#pragma unroll
    for (int j = 0; j < 32; ++j)
      pin[(size_t)(tile * 32 + j) * NW4 + w] = v[j] + toff;
    if (tile == 7) {
      unsigned tin = toff + s;      // packed in-degrees of the 4 nodes
      unsigned tout = 0;
#pragma unroll
      for (int k = 0; k < 8; ++k) tout += osum[k][wl];
      int i0 = tin & 0xffu, i1 = (tin >> 8) & 0xffu,
          i2 = (tin >> 16) & 0xffu, i3 = (tin >> 24) & 0xffu;
      int o0 = tout & 0xffu, o1 = (tout >> 8) & 0xffu,
          o2 = (tout >> 16) & 0xffu, o3 = (tout >> 24) & 0xffu;
      ((int4*)in_cnt)[w] = make_int4(i0, i1, i2, i3);
      ((float4*)nd)[w] = make_float4(rsqrtf((float)max(i0, 1)),
                                     rsqrtf((float)max(i1, 1)),
                                     rsqrtf((float)max(i2, 1)),
                                     rsqrtf((float)max(i3, 1)));
      ((float4*)ns)[w] = make_float4(rsqrtf((float)max(o0, 1)),
                                     rsqrtf((float)max(o1, 1)),
                                     rsqrtf((float)max(o2, 1)),
                                     rsqrtf((float)max(o3, 1)));
    }
  }
}

// ---------------------------------------------------------------------------
// Fused phase 3 (everything that depends only on merge, disjoint outputs):
//   blocks [0,256):    atomic-free CSR fill (padded, stride 64/node)
//   blocks [256,512):  weight transpose -> fp16 Wt[m][n][k]
//   blocks [512,...):  X0 = enc8(ns[row] * attr[row])  (ns prescaled)
// ---------------------------------------------------------------------------
__global__ __launch_bounds__(256) void fillprep_kernel(
    const int* __restrict__ src, const int* __restrict__ dst,
    const unsigned char* __restrict__ rank, const unsigned* __restrict__ pin,
    int* __restrict__ csr,
    const float* __restrict__ attr, const float* __restrict__ Ws,
    const float* __restrict__ decW, const float* __restrict__ ns,
    unsigned char* __restrict__ X, f16* __restrict__ Wt,
    int E, int chunk, int n4) {
  const int b = blockIdx.x;
  if (b < 256) {
    const int e0 = b * chunk, e1 = min(E, e0 + chunk);
    const unsigned* __restrict__ row = pin + (size_t)b * NW4;
    for (int e = e0 + threadIdx.x; e < e1; e += 256) {
      int s = src[e], d = dst[e];
      unsigned base = (row[d >> 2] >> (8u * (d & 3))) & 0xffu;
      csr[d * CST + (int)base + (int)rank[e]] = s;
    }
  } else if (b < 512) {
    int i = (b - 256) * 256 + threadIdx.x;    // exactly 4*128*128
    int m = i >> 14, rem = i & 16383, n = rem >> 7, k = rem & 127;
    const float* Wsrc = (m < 3) ? (Ws + (size_t)m * 16384) : decW;
    Wt[i] = (f16)Wsrc[k * 128 + n];
  } else {
    int i = (b - 512) * 256 + threadIdx.x;
    if (i < n4) {
      int r = i >> 5;
      float s = ns[r];
      float4 v = ((const float4*)attr)[i];
      ((uchar4*)X)[i] = make_uchar4(enc8(s * v.x), enc8(s * v.y),
                                    enc8(s * v.z), enc8(s * v.w));
    }
  }
}

__global__ void mask_h_kernel(unsigned char* __restrict__ h,
                              const int* __restrict__ mask,
                              const float* __restrict__ token,
                              const float* __restrict__ ns, int n4) {
  int i = blockIdx.x * blockDim.x + threadIdx.x;
  if (i < n4) {
    int r = i >> 5, c4 = i & 31;       // 32 uchar4 per 128-wide row
    int row = mask[r];
    float s = ns[row];
    float4 v = ((const float4*)token)[c4];
    *(uchar4*)(h + (size_t)row * HID + c4 * 4) =
        make_uchar4(enc8(s * v.x), enc8(s * v.y), enc8(s * v.z), enc8(s * v.w));
  }
}

// ---------------------------------------------------------------------------
// CSR aggregation (R8 structure RESTORED -- R9 proved fusing this into the
// GEMM destroys its latency hiding: one wave per node = 50000 independent
// waves is the resource). Whole padded csr row in ONE coalesced 64-lane
// load; __shfl feeds each edge's index with zero memory latency. X rows are
// fp8-e5m2 and ns-prescaled; fp32 accumulate; fp8 out.
// Y[v] = nd[v] * sum_{u in row} X[u].
// ---------------------------------------------------------------------------
__global__ __launch_bounds__(256) void agg_kernel(
    const unsigned short* __restrict__ X, const int* __restrict__ csr,
    const int* __restrict__ in_cnt, const float* __restrict__ nd,
    unsigned short* __restrict__ Y, int n) {
  int node = (blockIdx.x * blockDim.x + threadIdx.x) >> 6;
  int lane = threadIdx.x & 63;
  if (node >= n) return;
  int cnt = in_cnt[node];
  int idx = csr[node * CST + lane];   // whole padded row, one load
  float2 acc = make_float2(0.f, 0.f);
  int i = 0;
  for (; i + 4 <= cnt; i += 4) {
    int s0 = __shfl(idx, i + 0);
    int s1 = __shfl(idx, i + 1);
    int s2 = __shfl(idx, i + 2);
    int s3 = __shfl(idx, i + 3);
    float2 v0 = dec8x2(X[(size_t)s0 * 64 + lane]);
    float2 v1 = dec8x2(X[(size_t)s1 * 64 + lane]);
    float2 v2 = dec8x2(X[(size_t)s2 * 64 + lane]);
    float2 v3 = dec8x2(X[(size_t)s3 * 64 + lane]);
    acc.x += (v0.x + v1.x) + (v2.x + v3.x);
    acc.y += (v0.y + v1.y) + (v2.y + v3.y);
  }
  for (; i < cnt; ++i) {
    int s = __shfl(idx, i);
    float2 v = dec8x2(X[(size_t)s * 64 + lane]);
    acc.x += v.x;
    acc.y += v.y;
  }
  float ndv = nd[node];
  unsigned char lo = enc8(acc.x * ndv), hi = enc8(acc.y * ndv);
  Y[(size_t)node * 64 + lane] = (unsigned short)(lo | (hi << 8));
}

// ---------------------------------------------------------------------------
// MFMA fp16 GEMM (layers): X' = relu(Y @ W + b)[, * ns[row]] -> fp8.
// A (Y) is fp8-e5m2, decoded to f16 in registers. W pre-transposed Wt[n][k].
// Block = 4 waves x 16 rows; 8 n-tiles x 4 k-iters mfma_f32_16x16x32_f16.
// B-tile LDS stride 136 halves (2-way = free). row_scale = ns for layers
// feeding another agg (prescale), null for the last layer (decoder input).
// Layouts (HW-verified): A[m=lane&15][k=(lane>>4)*8+j]; C/D col=lane&15,
// row=(lane>>4)*4+reg.
// ---------------------------------------------------------------------------
__global__ __launch_bounds__(256) void gemm_layer_kernel(
    const unsigned char* __restrict__ A8, const f16* __restrict__ Wt,
    unsigned char* __restrict__ out, const float* __restrict__ col_bias,
    const float* __restrict__ row_scale, int M) {
  __shared__ f16 Bs[128 * 136];     // 34.8 KB
  const int t = threadIdx.x;
  for (int i = t; i < 2048; i += 256) {
    int n = i >> 4, c = i & 15;
    *(f16x8*)&Bs[n * 136 + c * 8] = *(const f16x8*)&Wt[n * 128 + c * 8];
  }
  const int wave = t >> 6, lane = t & 63;
  const int ln = lane & 15, kq = lane >> 4;
  const int mBase = blockIdx.x * 64 + wave * 16;

  const int am = mBase + ln;
  const int rowA = (am < M) ? am : 0;
  const unsigned char* Ap = A8 + (size_t)rowA * HID + kq * 8;
  f16x8 af[4];
#pragma unroll
  for (int ki = 0; ki < 4; ++ki) af[ki] = dec8x8(Ap + ki * 32);

  f32x4 acc[8];
#pragma unroll
  for (int nt = 0; nt < 8; ++nt) acc[nt] = (f32x4){0.f, 0.f, 0.f, 0.f};
  __syncthreads();
#pragma unroll
  for (int ki = 0; ki < 4; ++ki) {
#pragma unroll
    for (int nt = 0; nt < 8; ++nt) {
      f16x8 bf = *(const f16x8*)&Bs[(nt * 16 + ln) * 136 + ki * 32 + kq * 8];
      acc[nt] = __builtin_amdgcn_mfma_f32_16x16x32_f16(af[ki], bf, acc[nt], 0, 0, 0);
    }
  }
  const int orow = mBase + kq * 4;
  float rs[4];
#pragma unroll
  for (int r = 0; r < 4; ++r)
    rs[r] = (row_scale && orow + r < M) ? row_scale[orow + r] : 1.f;
#pragma unroll
  for (int nt = 0; nt < 8; ++nt) {
    int col = nt * 16 + ln;
    float bb = col_bias[col];
#pragma unroll
    for (int r = 0; r < 4; ++r) {
      int gr = orow + r;
      if (gr < M) {
        float v = fmaxf(acc[nt][r] + bb, 0.f) * rs[r];
        out[(size_t)gr * HID + col] = enc8(v);
      }
    }
  }
}

// ---------------------------------------------------------------------------
// Decoder GEMM with FUSED loss: recon rows never hit memory. Per block:
// acc -> (recon - attr[mask[row]])^2 -> wave reduce -> one atomic.
// ---------------------------------------------------------------------------
__global__ __launch_bounds__(256) void gemm_loss_kernel(
    const unsigned char* __restrict__ A8, const f16* __restrict__ Wt,
    const float* __restrict__ col_bias, const int* __restrict__ gather,
    const float* __restrict__ attr, float* __restrict__ out, int M, float scale) {
  __shared__ f16 Bs[128 * 136];
  const int t = threadIdx.x;
  for (int i = t; i < 2048; i += 256) {
    int n = i >> 4, c = i & 15;
    *(f16x8*)&Bs[n * 136 + c * 8] = *(const f16x8*)&Wt[n * 128 + c * 8];
  }
  const int wave = t >> 6, lane = t & 63;
  const int ln = lane & 15, kq = lane >> 4;
  const int mBase = blockIdx.x * 64 + wave * 16;

  const int am = mBase + ln;
  const int rowA = (am < M) ? gather[am] : 0;
  const unsigned char* Ap = A8 + (size_t)rowA * HID + kq * 8;
  f16x8 af[4];
#pragma unroll
  for (int ki = 0; ki < 4; ++ki) af[ki] = dec8x8(Ap + ki * 32);

  f32x4 acc[8];
#pragma unroll
  for (int nt = 0; nt < 8; ++nt) acc[nt] = (f32x4){0.f, 0.f, 0.f, 0.f};
  __syncthreads();
#pragma unroll
  for (int ki = 0; ki < 4; ++ki) {
#pragma unroll
    for (int nt = 0; nt < 8; ++nt) {
      f16x8 bf = *(const f16x8*)&Bs[(nt * 16 + ln) * 136 + ki * 32 + kq * 8];
      acc[nt] = __builtin_amdgcn_mfma_f32_16x16x32_f16(af[ki], bf, acc[nt], 0, 0, 0);
    }
  }
  const int orow = mBase + kq * 4;
  int mrow[4];
#pragma unroll
  for (int r = 0; r < 4; ++r) mrow[r] = (orow + r < M) ? gather[orow + r] : -1;
  float part = 0.f;
#pragma unroll
  for (int nt = 0; nt < 8; ++nt) {
    int col = nt * 16 + ln;
    float bb = col_bias[col];
#pragma unroll
    for (int r = 0; r < 4; ++r) {
      if (mrow[r] >= 0) {
        float d = acc[nt][r] + bb - attr[(size_t)mrow[r] * HID + col];
        part += d * d;
      }
    }
  }
#pragma unroll
  for (int off = 32; off > 0; off >>= 1) part += __shfl_down(part, off);
  __shared__ float wsum[4];
  if (lane == 0) wsum[wave] = part;
  __syncthreads();
  if (t == 0)
    atomicAdd(out, (wsum[0] + wsum[1] + wsum[2] + wsum[3]) * scale);
}

// ---------------------------------------------------------------------------
extern "C" void kernel_launch(void* const* d_in, const int* in_sizes, int n_in,
                              void* d_out, int out_size, void* d_ws, size_t ws_size,
                              hipStream_t stream) {
  const float* attr  = (const float*)d_in[0];
  const int*   src   = (const int*)d_in[1];
  const int*   dst   = (const int*)d_in[2];
  const float* Ws    = (const float*)d_in[3];
  const float* bs    = (const float*)d_in[4];
  const float* decW  = (const float*)d_in[5];
  const float* decb  = (const float*)d_in[6];
  const float* token = (const float*)d_in[7];
  const int*   mask  = (const int*)d_in[8];

  const int N  = in_sizes[0] / HID;   // 50000
  const int E  = in_sizes[1];         // 800000
  const int NM = in_sizes[8];         // 15000
  const int chunk = (E + NB - 1) / NB;  // 3125

  // Workspace layout (16B-aligned pieces; total ~53 MB)
  char* w = (char*)d_ws;
  unsigned char* X = (unsigned char*)w;  w += (size_t)N * HID;  // fp8 features
  unsigned char* Y = (unsigned char*)w;  w += (size_t)N * HID;  // fp8 agg out
  f16* Wt = (f16*)w;           w += (size_t)4 * HID * HID * 2;
  int* csr = (int*)w;          w += (size_t)NN * CST * 4;       // padded CSR
  unsigned char* rank = (unsigned char*)w;  w += (size_t)E;
  unsigned* pin = (unsigned*)w;  w += (size_t)NB * NW4 * 4;
  unsigned* pout = (unsigned*)w; w += (size_t)NB * NW4 * 4;
  int* in_cnt = (int*)w;       w += (size_t)N * 4;
  float* ns = (float*)w;       w += (size_t)N * 4;
  float* nd = (float*)w;       w += (size_t)N * 4;

  hist_kernel<<<NB, 256, 0, stream>>>(src, dst, pin, pout, rank,
                                      (float*)d_out, E, chunk);
  merge_kernel<<<(NW4 + 31) / 32, 256, 0, stream>>>(pin, pout, in_cnt, ns, nd);

  int prep_blocks = 512 + (N * 32 + 255) / 256;
  fillprep_kernel<<<prep_blocks, 256, 0, stream>>>(
      src, dst, rank, pin, csr, attr, Ws, decW, ns, X, Wt, E, chunk, N * 32);
  mask_h_kernel<<<(NM * 32 + 255) / 256, 256, 0, stream>>>(X, mask, token, ns, NM * 32);

  for (int l = 0; l < 3; ++l) {
    // Y = nd * Agg(X)            (X already ns-prescaled)
    agg_kernel<<<(N + 3) / 4, 256, 0, stream>>>(
        (const unsigned short*)X, csr, in_cnt, nd, (unsigned short*)Y, N);
    // X = relu(Y @ W_l + b_l) [* ns for l<2]   (fp8 out)
    gemm_layer_kernel<<<(N + 63) / 64, 256, 0, stream>>>(
        Y, Wt + (size_t)l * HID * HID, X, bs + (size_t)l * HID,
        (l < 2) ? ns : nullptr, N);
  }

  // loss = mean((X[mask] @ decW + decb - attr[mask])^2), recon never stored
  gemm_loss_kernel<<<(NM + 63) / 64, 256, 0, stream>>>(
      X, Wt + (size_t)3 * HID * HID, decb, mask, attr, (float*)d_out,
      NM, 1.f / ((float)NM * HID));
}